// Round 15
// baseline (184.250 us; speedup 1.0000x reference)
//
#include <hip/hip_runtime.h>

namespace {
constexpr int NN  = 100000;   // nodes
constexpr int NE  = 1000000;  // edges
constexpr int INF = 256;
constexpr int HF  = 64;
constexpr int OF  = 16;
constexpr int SCAN_CHUNK = 1024;                       // elems per scan block (256 thr x 4)
constexpr int NBLK = (NN + SCAN_CHUNK - 1) / SCAN_CHUNK; // 98
constexpr int NSEG = 8;       // dst segments, pinned to XCDs via blockIdx%8
constexpr int SEGW = (NN + NSEG - 1) / NSEG;             // 12500 nodes / segment
constexpr int CNTW = 100096;  // padded cnt/cursor width (ints)
constexpr int ZBLK = (CNTW / 4 + 255) / 256;             // 98 zero-blocks
constexpr int GB   = (NN + 127) / 128;                   // 782 gemm1 blocks
constexpr int ECHUNK = 2048;  // edges per hist/scatter block (8 per thread)
constexpr int EGRP = (NE + ECHUNK - 1) / ECHUNK;         // 489 chunk groups
constexpr int SB   = EGRP * NSEG;                        // 3912 scatter blocks
}

typedef __attribute__((ext_vector_type(8))) short     sh8;
typedef __attribute__((ext_vector_type(4))) float     f32x4;
typedef __attribute__((ext_vector_type(8))) unsigned short us8;

__device__ __forceinline__ unsigned short f2bf(float f) {
    unsigned int u = __builtin_bit_cast(unsigned int, f);
    u += 0x7FFFu + ((u >> 16) & 1u);       // round-to-nearest-even
    return (unsigned short)(u >> 16);
}
__device__ __forceinline__ float bf2f(unsigned short s) {
    return __builtin_bit_cast(float, (unsigned int)s << 16);
}

// ---- pre: zero cnt + W1 -> bf16 transposed, one launch ---------------------
__global__ void k_pre(int* __restrict__ cnt, const float* __restrict__ W1,
                      unsigned short* __restrict__ wt_g) {
    int b = blockIdx.x, t = threadIdx.x;
    if (b < ZBLK) {
        int i = (b * 256 + t) * 4;
        if (i < CNTW) *(int4*)(cnt + i) = (int4){0, 0, 0, 0};
    } else {
        int idx = (b - ZBLK) * 256 + t;       // 16384 tasks
        int c = idx >> 8, k = idx & 255;
        wt_g[idx] = f2bf(W1[(size_t)k * HF + c]);
    }
}

// ---- degree histogram: 8 edges/thread, XCD-pinned dst segments -------------
__global__ __launch_bounds__(256) void k_hist(const int* __restrict__ dst,
                                              int* __restrict__ cnt) {
    int b   = blockIdx.x;
    int seg = b & (NSEG - 1);
    int grp = b >> 3;
    int e0  = grp * ECHUNK + threadIdx.x;
    int d[8];
    #pragma unroll
    for (int i = 0; i < 8; ++i) {
        int e = e0 + i * 256;
        d[i] = (e < NE) ? dst[e] : -1;    // -1 -> never matches a segment
    }
    #pragma unroll
    for (int i = 0; i < 8; ++i) {
        if ((unsigned)d[i] / (unsigned)SEGW == (unsigned)seg)
            atomicAdd(&cnt[d[i]], 1);
    }
}

// ---- block-reduce of cnt -> bsum, fused dinv = rsqrt(cnt+1) ----------------
__global__ __launch_bounds__(256) void k_reduce(const int* __restrict__ cnt,
                                                int* __restrict__ bsum,
                                                float* __restrict__ dinv) {
    int t = threadIdx.x;
    int i0 = blockIdx.x * SCAN_CHUNK + t * 4;
    int s = 0;
    float dv[4] = {0.f, 0.f, 0.f, 0.f};
    #pragma unroll
    for (int q = 0; q < 4; ++q) {
        if (i0 + q < NN) {
            int c = cnt[i0 + q];
            s += c;
            dv[q] = rsqrtf((float)(c + 1));
        }
    }
    if (i0 + 3 < NN) *(float4*)(dinv + i0) = (float4){dv[0], dv[1], dv[2], dv[3]};
    else { for (int q = 0; q < 4; ++q) if (i0 + q < NN) dinv[i0 + q] = dv[q]; }
    #pragma unroll
    for (int off = 32; off > 0; off >>= 1) s += __shfl_down(s, off);
    __shared__ int wsum[4];
    int lane = t & 63, wid = t >> 6;
    if (lane == 0) wsum[wid] = s;
    __syncthreads();
    if (t == 0) bsum[blockIdx.x] = wsum[0] + wsum[1] + wsum[2] + wsum[3];
}

// ---- scan: each block derives its own prefix from bsum (no partials pass) --
__global__ __launch_bounds__(256) void k_scan(const int* __restrict__ cnt,
                                              const int* __restrict__ bsum,
                                              int* __restrict__ rowptr,
                                              int* __restrict__ cursor) {
    int t = threadIdx.x;
    int b = blockIdx.x;
    int lane = t & 63, wid = t >> 6;

    int p = 0;
    if (lane < b) p += bsum[lane];
    if (64 + lane < b) p += bsum[64 + lane];
    #pragma unroll
    for (int off = 32; off > 0; off >>= 1) p += __shfl_down(p, off);
    int blockBase = __shfl(p, 0);

    int i0 = b * SCAN_CHUNK + t * 4;
    int v0 = 0, v1 = 0, v2 = 0, v3 = 0;
    if (i0 + 0 < NN) v0 = cnt[i0 + 0];
    if (i0 + 1 < NN) v1 = cnt[i0 + 1];
    if (i0 + 2 < NN) v2 = cnt[i0 + 2];
    if (i0 + 3 < NN) v3 = cnt[i0 + 3];
    int tsum = v0 + v1 + v2 + v3;
    int incl = tsum;
    #pragma unroll
    for (int off = 1; off < 64; off <<= 1) {
        int n = __shfl_up(incl, off);
        if (lane >= off) incl += n;
    }
    __shared__ int wsum[4];
    if (lane == 63) wsum[wid] = incl;
    __syncthreads();
    int woff = 0;
    for (int w = 0; w < wid; ++w) woff += wsum[w];
    int excl = woff + (incl - tsum) + blockBase;
    int e0 = excl, e1 = e0 + v0, e2 = e1 + v1, e3 = e2 + v2;
    if (i0 + 0 < NN) { rowptr[i0 + 0] = e0; cursor[i0 + 0] = e0; }
    if (i0 + 1 < NN) { rowptr[i0 + 1] = e1; cursor[i0 + 1] = e1; }
    if (i0 + 2 < NN) { rowptr[i0 + 2] = e2; cursor[i0 + 2] = e2; }
    if (i0 + 3 < NN) { rowptr[i0 + 3] = e3; cursor[i0 + 3] = e3; }
    if (i0 + 3 == NN - 1) rowptr[NN] = e3 + v3;
}

// ---- FUSED: gemm1 (blocks 0..GB-1) || scatter (blocks GB..) ----------------
// gemm1 path: depth-4 software-pipelined x loads. Body order is
// COMPUTE(it-4) THEN LOAD(it) — load into buf[it&3] would otherwise
// overwrite the buffer the compute stage is about to read (R14 bug).
__global__ __launch_bounds__(256, 4) void k_gs(const float* __restrict__ x,
                                               const unsigned short* __restrict__ wt_g,
                                               unsigned short* __restrict__ h1,
                                               const int* __restrict__ src,
                                               const int* __restrict__ dst,
                                               int* __restrict__ cursor,
                                               int* __restrict__ eidx) {
    __shared__ unsigned short wt[64 * 264];    // stride 264: 2-way bank alias (free)
    int b = blockIdx.x;
    int t = threadIdx.x;

    if (b >= GB) {
        // ---- scatter path ----
        int sb  = b - GB;
        int seg = sb & (NSEG - 1);
        int grp = sb >> 3;
        int e0  = grp * ECHUNK + t;
        int d[8];
        #pragma unroll
        for (int i = 0; i < 8; ++i) {
            int e = e0 + i * 256;
            d[i] = (e < NE) ? dst[e] : -1;
        }
        #pragma unroll
        for (int i = 0; i < 8; ++i) {
            if ((unsigned)d[i] / (unsigned)SEGW == (unsigned)seg) {
                int p = atomicAdd(&cursor[d[i]], 1);
                eidx[p] = src[e0 + i * 256];
            }
        }
        return;
    }

    // ---- gemm1 path ----
    int w = t >> 6, l = t & 63;
    int row0 = b * 128;

    #pragma unroll
    for (int p = 0; p < 8; ++p) {
        int T   = p * 256 + t;
        int c   = T >> 5;
        int kb8 = T & 31;
        *(us8*)(wt + c * 264 + kb8 * 8) = *(const us8*)(wt_g + c * 256 + kb8 * 8);
    }
    __syncthreads();

    int m = l & 15;
    int g = l >> 4;
    int gr0 = row0 + w * 32 + m;      if (gr0 > NN - 1) gr0 = NN - 1;
    int gr1 = row0 + w * 32 + 16 + m; if (gr1 > NN - 1) gr1 = NN - 1;
    const float* p0 = x + (size_t)gr0 * INF + g * 8;
    const float* p1 = x + (size_t)gr1 * INF + g * 8;

    f32x4 acc[2][4];
    #pragma unroll
    for (int i = 0; i < 2; ++i)
        #pragma unroll
        for (int j = 0; j < 4; ++j) acc[i][j] = (f32x4){0.f, 0.f, 0.f, 0.f};

    // depth-4 software pipeline, COMPUTE-BEFORE-LOAD body ordering.
    float4 buf[4][4];
    #pragma unroll
    for (int it = 0; it < 12; ++it) {
        if (it >= 4) {
            int kb = (it - 4) * 32;
            float4 v0 = buf[(it - 4) & 3][0];
            float4 v1 = buf[(it - 4) & 3][1];
            float4 v2 = buf[(it - 4) & 3][2];
            float4 v3 = buf[(it - 4) & 3][3];
            us8 a0u = { f2bf(v0.x), f2bf(v0.y), f2bf(v0.z), f2bf(v0.w),
                        f2bf(v1.x), f2bf(v1.y), f2bf(v1.z), f2bf(v1.w) };
            us8 a1u = { f2bf(v2.x), f2bf(v2.y), f2bf(v2.z), f2bf(v2.w),
                        f2bf(v3.x), f2bf(v3.y), f2bf(v3.z), f2bf(v3.w) };
            sh8 a0 = __builtin_bit_cast(sh8, a0u);
            sh8 a1 = __builtin_bit_cast(sh8, a1u);
            #pragma unroll
            for (int nt = 0; nt < 4; ++nt) {
                sh8 bb = *(const sh8*)(wt + (nt * 16 + m) * 264 + kb + g * 8);
                acc[0][nt] = __builtin_amdgcn_mfma_f32_16x16x32_bf16(a0, bb, acc[0][nt], 0, 0, 0);
                acc[1][nt] = __builtin_amdgcn_mfma_f32_16x16x32_bf16(a1, bb, acc[1][nt], 0, 0, 0);
            }
        }
        if (it < 8) {
            int kb = it * 32;
            buf[it & 3][0] = *(const float4*)(p0 + kb);
            buf[it & 3][1] = *(const float4*)(p0 + kb + 4);
            buf[it & 3][2] = *(const float4*)(p1 + kb);
            buf[it & 3][3] = *(const float4*)(p1 + kb + 4);
        }
    }

    #pragma unroll
    for (int mt = 0; mt < 2; ++mt) {
        #pragma unroll
        for (int r = 0; r < 4; ++r) {
            int gr = row0 + w * 32 + mt * 16 + (l >> 4) * 4 + r;
            if (gr < NN) {
                #pragma unroll
                for (int nt = 0; nt < 4; ++nt)
                    h1[(size_t)gr * HF + nt * 16 + (l & 15)] = f2bf(acc[mt][nt][r]);
            }
        }
    }
}

// ---- Gather layer 1: 8 nodes/wave, 8 lanes/node, lane owns 8 feats ---------
__global__ __launch_bounds__(256) void k_gather1(const int* __restrict__ rowptr,
                                                 const int* __restrict__ eidx,
                                                 const float* __restrict__ dinv,
                                                 const unsigned short* __restrict__ h1,
                                                 const float* __restrict__ b1,
                                                 const float* __restrict__ W2,
                                                 unsigned short* __restrict__ h2) {
    __shared__ float w2L[HF * OF];     // 4KB, [k][j]
    __shared__ float hrL[32][HF + 4];  // 8.5KB, stride 68 (bank-spread)
    int t = threadIdx.x;
    *(float4*)(w2L + t * 4) = *(const float4*)(W2 + t * 4);   // 256*4 = 1024 ✓

    int nodeL = t >> 3;           // 0..31: node within block
    int fg    = t & 7;            // feature octet: feats fg*8..fg*8+7
    int v     = blockIdx.x * 32 + nodeL;   // NN = 3125*32 exact
    int beg = rowptr[v], end = rowptr[v + 1];

    float acc[8] = {};
    int   s_n = 0;  float w_n = 0.f;  us8 h_n = {};
    if (beg < end) {
        s_n = eidx[beg];
        w_n = dinv[s_n];
        h_n = *(const us8*)(h1 + (size_t)s_n * HF + fg * 8);
    }
    for (int i = beg; i < end; ++i) {
        float w_c = w_n;  us8 h_c = h_n;
        if (i + 1 < end) {
            s_n = eidx[i + 1];
            w_n = dinv[s_n];
            h_n = *(const us8*)(h1 + (size_t)s_n * HF + fg * 8);
        }
        #pragma unroll
        for (int q = 0; q < 8; ++q) acc[q] += w_c * bf2f(h_c[q]);
    }

    {
        float dv = dinv[v], sl = dv * dv;
        us8 hv = *(const us8*)(h1 + (size_t)v * HF + fg * 8);
        #pragma unroll
        for (int q = 0; q < 8; ++q) {
            float val = dv * acc[q] + sl * bf2f(hv[q]) + b1[fg * 8 + q];
            hrL[nodeL][fg * 8 + q] = val > 0.f ? val : 0.f;
        }
    }
    __syncthreads();

    #pragma unroll
    for (int T = t; T < 512; T += 256) {
        int n = T >> 4, j = T & 15;
        const float* hr = hrL[n];
        float p = 0.f;
        #pragma unroll
        for (int k = 0; k < HF; ++k) p += hr[k] * w2L[k * OF + j];
        h2[(size_t)(blockIdx.x * 32 + n) * OF + j] = f2bf(p);
    }
}

// ---- Gather layer 2: 16 nodes/block, 16 lanes/node, lane owns 1 out-feat ---
__global__ __launch_bounds__(256) void k_gather2(const int* __restrict__ rowptr,
                                                 const int* __restrict__ eidx,
                                                 const float* __restrict__ dinv,
                                                 const unsigned short* __restrict__ h2,
                                                 const float* __restrict__ b2,
                                                 float* __restrict__ out) {
    int t     = threadIdx.x;
    int nodeL = t >> 4;           // 0..15
    int j     = t & 15;           // out-feature
    int v     = blockIdx.x * 16 + nodeL;   // NN = 6250*16 exact
    int beg = rowptr[v], end = rowptr[v + 1];

    float acc = 0.f;
    int   s_n = 0;  float w_n = 0.f;  unsigned short h_n = 0;
    if (beg < end) {
        s_n = eidx[beg];
        w_n = dinv[s_n];
        h_n = h2[(size_t)s_n * OF + j];
    }
    for (int i = beg; i < end; ++i) {
        float w_c = w_n;  unsigned short h_c = h_n;
        if (i + 1 < end) {
            s_n = eidx[i + 1];
            w_n = dinv[s_n];
            h_n = h2[(size_t)s_n * OF + j];
        }
        acc += w_c * bf2f(h_c);
    }
    float dv = dinv[v];
    out[(size_t)v * OF + j] = dv * acc + dv * dv * bf2f(h2[(size_t)v * OF + j]) + b2[j];
}

extern "C" void kernel_launch(void* const* d_in, const int* in_sizes, int n_in,
                              void* d_out, int out_size, void* d_ws, size_t ws_size,
                              hipStream_t stream) {
    const float* x   = (const float*)d_in[0];
    const int*   ei  = (const int*)d_in[1];
    const int*   src = ei;            // edge_index[0]
    const int*   dst = ei + NE;       // edge_index[1]
    const float* W1  = (const float*)d_in[2];
    const float* b1  = (const float*)d_in[3];
    const float* W2  = (const float*)d_in[4];
    const float* b2  = (const float*)d_in[5];
    float* out = (float*)d_out;

    // workspace layout (4B units unless noted)
    float* dinv  = (float*)d_ws;                           // [CNTW]
    unsigned short* h1b = (unsigned short*)(dinv + CNTW);  // [NN*64] bf16 (3.2M ints)
    unsigned short* h2b = (unsigned short*)(h1b + (size_t)NN * HF);  // [NN*16] bf16
    int*   cnt   = (int*)(h2b + (size_t)NN * OF + (size_t)NN * OF);  // [CNTW]
    int*   rowptr = cnt + CNTW;                            // [100352]
    int*   cursor = rowptr + 100352;                       // [CNTW]
    int*   eidx  = cursor + CNTW;                          // [NE]
    int*   bsum  = eidx + NE;                              // [128]
    unsigned short* wt_g = (unsigned short*)(bsum + 128);  // [64*256] bf16

    // CSR build + norms + W pre-transpose
    k_pre<<<ZBLK + 64, 256, 0, stream>>>(cnt, W1, wt_g);
    k_hist<<<SB, 256, 0, stream>>>(dst, cnt);
    k_reduce<<<NBLK, 256, 0, stream>>>(cnt, bsum, dinv);
    k_scan<<<NBLK, 256, 0, stream>>>(cnt, bsum, rowptr, cursor);

    // gemm1 || scatter in one launch (independent work, overlap on one stream)
    k_gs<<<GB + SB, 256, 0, stream>>>(x, wt_g, h1b, src, dst, cursor, eidx);

    // layer 1 aggregation (+ fused layer-2 GEMM)
    k_gather1<<<NN / 32, 256, 0, stream>>>(rowptr, eidx, dinv, h1b, b1, W2, h2b);

    // layer 2 aggregation
    k_gather2<<<NN / 16, 256, 0, stream>>>(rowptr, eidx, dinv, h2b, b2, out);
}

// Round 16
// 180.270 us; speedup vs baseline: 1.0221x; 1.0221x over previous
//
#include <hip/hip_runtime.h>

namespace {
constexpr int NN  = 100000;   // nodes
constexpr int NE  = 1000000;  // edges
constexpr int INF = 256;
constexpr int HF  = 64;
constexpr int OF  = 16;
constexpr int SCAN_CHUNK = 1024;                       // elems per scan block (256 thr x 4)
constexpr int NBLK = (NN + SCAN_CHUNK - 1) / SCAN_CHUNK; // 98
constexpr int NSEG = 8;       // dst segments, pinned to XCDs via blockIdx%8
constexpr int SEGW = (NN + NSEG - 1) / NSEG;             // 12500 nodes / segment
constexpr int CNTW = 100096;  // padded cnt/cursor width (ints)
constexpr int ZBLK = (CNTW / 4 + 255) / 256;             // 98 zero-blocks
constexpr int GB   = (NN + 127) / 128;                   // 782 gemm1 blocks
constexpr int ECHUNK = 2048;  // edges per hist/scatter block (8 per thread)
constexpr int EGRP = (NE + ECHUNK - 1) / ECHUNK;         // 489 chunk groups
constexpr int SB   = EGRP * NSEG;                        // 3912 scatter blocks
}

typedef __attribute__((ext_vector_type(8))) short     sh8;
typedef __attribute__((ext_vector_type(4))) float     f32x4;
typedef __attribute__((ext_vector_type(8))) unsigned short us8;

__device__ __forceinline__ unsigned short f2bf(float f) {
    unsigned int u = __builtin_bit_cast(unsigned int, f);
    u += 0x7FFFu + ((u >> 16) & 1u);       // round-to-nearest-even
    return (unsigned short)(u >> 16);
}
__device__ __forceinline__ float bf2f(unsigned short s) {
    return __builtin_bit_cast(float, (unsigned int)s << 16);
}

// ---- pre: zero cnt + W1 -> bf16 transposed, one launch ---------------------
__global__ void k_pre(int* __restrict__ cnt, const float* __restrict__ W1,
                      unsigned short* __restrict__ wt_g) {
    int b = blockIdx.x, t = threadIdx.x;
    if (b < ZBLK) {
        int i = (b * 256 + t) * 4;
        if (i < CNTW) *(int4*)(cnt + i) = (int4){0, 0, 0, 0};
    } else {
        int idx = (b - ZBLK) * 256 + t;       // 16384 tasks
        int c = idx >> 8, k = idx & 255;
        wt_g[idx] = f2bf(W1[(size_t)k * HF + c]);
    }
}

// ---- degree histogram: 8 edges/thread, XCD-pinned dst segments -------------
__global__ __launch_bounds__(256) void k_hist(const int* __restrict__ dst,
                                              int* __restrict__ cnt) {
    int b   = blockIdx.x;
    int seg = b & (NSEG - 1);
    int grp = b >> 3;
    int e0  = grp * ECHUNK + threadIdx.x;
    int d[8];
    #pragma unroll
    for (int i = 0; i < 8; ++i) {
        int e = e0 + i * 256;
        d[i] = (e < NE) ? dst[e] : -1;    // -1 -> never matches a segment
    }
    #pragma unroll
    for (int i = 0; i < 8; ++i) {
        if ((unsigned)d[i] / (unsigned)SEGW == (unsigned)seg)
            atomicAdd(&cnt[d[i]], 1);
    }
}

// ---- block-reduce of cnt -> bsum, fused dinv = rsqrt(cnt+1) ----------------
__global__ __launch_bounds__(256) void k_reduce(const int* __restrict__ cnt,
                                                int* __restrict__ bsum,
                                                float* __restrict__ dinv) {
    int t = threadIdx.x;
    int i0 = blockIdx.x * SCAN_CHUNK + t * 4;
    int s = 0;
    float dv[4] = {0.f, 0.f, 0.f, 0.f};
    #pragma unroll
    for (int q = 0; q < 4; ++q) {
        if (i0 + q < NN) {
            int c = cnt[i0 + q];
            s += c;
            dv[q] = rsqrtf((float)(c + 1));
        }
    }
    if (i0 + 3 < NN) *(float4*)(dinv + i0) = (float4){dv[0], dv[1], dv[2], dv[3]};
    else { for (int q = 0; q < 4; ++q) if (i0 + q < NN) dinv[i0 + q] = dv[q]; }
    #pragma unroll
    for (int off = 32; off > 0; off >>= 1) s += __shfl_down(s, off);
    __shared__ int wsum[4];
    int lane = t & 63, wid = t >> 6;
    if (lane == 0) wsum[wid] = s;
    __syncthreads();
    if (t == 0) bsum[blockIdx.x] = wsum[0] + wsum[1] + wsum[2] + wsum[3];
}

// ---- scan: each block derives its own prefix from bsum (no partials pass) --
__global__ __launch_bounds__(256) void k_scan(const int* __restrict__ cnt,
                                              const int* __restrict__ bsum,
                                              int* __restrict__ rowptr,
                                              int* __restrict__ cursor) {
    int t = threadIdx.x;
    int b = blockIdx.x;
    int lane = t & 63, wid = t >> 6;

    int p = 0;
    if (lane < b) p += bsum[lane];
    if (64 + lane < b) p += bsum[64 + lane];
    #pragma unroll
    for (int off = 32; off > 0; off >>= 1) p += __shfl_down(p, off);
    int blockBase = __shfl(p, 0);

    int i0 = b * SCAN_CHUNK + t * 4;
    int v0 = 0, v1 = 0, v2 = 0, v3 = 0;
    if (i0 + 0 < NN) v0 = cnt[i0 + 0];
    if (i0 + 1 < NN) v1 = cnt[i0 + 1];
    if (i0 + 2 < NN) v2 = cnt[i0 + 2];
    if (i0 + 3 < NN) v3 = cnt[i0 + 3];
    int tsum = v0 + v1 + v2 + v3;
    int incl = tsum;
    #pragma unroll
    for (int off = 1; off < 64; off <<= 1) {
        int n = __shfl_up(incl, off);
        if (lane >= off) incl += n;
    }
    __shared__ int wsum[4];
    if (lane == 63) wsum[wid] = incl;
    __syncthreads();
    int woff = 0;
    for (int w = 0; w < wid; ++w) woff += wsum[w];
    int excl = woff + (incl - tsum) + blockBase;
    int e0 = excl, e1 = e0 + v0, e2 = e1 + v1, e3 = e2 + v2;
    if (i0 + 0 < NN) { rowptr[i0 + 0] = e0; cursor[i0 + 0] = e0; }
    if (i0 + 1 < NN) { rowptr[i0 + 1] = e1; cursor[i0 + 1] = e1; }
    if (i0 + 2 < NN) { rowptr[i0 + 2] = e2; cursor[i0 + 2] = e2; }
    if (i0 + 3 < NN) { rowptr[i0 + 3] = e3; cursor[i0 + 3] = e3; }
    if (i0 + 3 == NN - 1) rowptr[NN] = e3 + v3;
}

// ---- FUSED: gemm1 (blocks 0..GB-1) || scatter (blocks GB..) ----------------
// K staged in two 128-halves -> LDS 17.4KB -> 8 blocks/CU (32 waves/CU, chip
// max) for BOTH paths. gemm1 hides x latency via TLP (the mechanism that
// works on CDNA4 — source-level ILP pipelines get rescheduled by hipcc,
// proven null in R13/R15). Scatter path regains its standalone concurrency.
__global__ __launch_bounds__(256, 8) void k_gs(const float* __restrict__ x,
                                               const unsigned short* __restrict__ wt_g,
                                               unsigned short* __restrict__ h1,
                                               const int* __restrict__ src,
                                               const int* __restrict__ dst,
                                               int* __restrict__ cursor,
                                               int* __restrict__ eidx) {
    __shared__ unsigned short wt[64 * 136];    // 17.4KB half-K tile
    int b = blockIdx.x;
    int t = threadIdx.x;

    if (b >= GB) {
        // ---- scatter path (no LDS use; now 8 blocks/CU) ----
        int sb  = b - GB;
        int seg = sb & (NSEG - 1);
        int grp = sb >> 3;
        int e0  = grp * ECHUNK + t;
        int d[8];
        #pragma unroll
        for (int i = 0; i < 8; ++i) {
            int e = e0 + i * 256;
            d[i] = (e < NE) ? dst[e] : -1;
        }
        #pragma unroll
        for (int i = 0; i < 8; ++i) {
            if ((unsigned)d[i] / (unsigned)SEGW == (unsigned)seg) {
                int p = atomicAdd(&cursor[d[i]], 1);
                eidx[p] = src[e0 + i * 256];
            }
        }
        return;
    }

    // ---- gemm1 path ----
    int w = t >> 6, l = t & 63;
    int row0 = b * 128;
    int m = l & 15;
    int g = l >> 4;
    int gr0 = row0 + w * 32 + m;      if (gr0 > NN - 1) gr0 = NN - 1;
    int gr1 = row0 + w * 32 + 16 + m; if (gr1 > NN - 1) gr1 = NN - 1;
    const float* p0 = x + (size_t)gr0 * INF + g * 8;
    const float* p1 = x + (size_t)gr1 * INF + g * 8;

    f32x4 acc[2][4];
    #pragma unroll
    for (int i = 0; i < 2; ++i)
        #pragma unroll
        for (int j = 0; j < 4; ++j) acc[i][j] = (f32x4){0.f, 0.f, 0.f, 0.f};

    #pragma unroll
    for (int half = 0; half < 2; ++half) {
        __syncthreads();   // protect previous half's reads before restage
        // stage this half's W tile: 64 cols x 128 k (1024 us8 chunks)
        #pragma unroll
        for (int p = 0; p < 4; ++p) {
            int T   = p * 256 + t;
            int c   = T >> 4;             // 0..63
            int kb8 = T & 15;             // 0..15
            *(us8*)(wt + c * 136 + kb8 * 8) =
                *(const us8*)(wt_g + c * 256 + half * 128 + kb8 * 8);
        }
        __syncthreads();

        #pragma unroll
        for (int kb = 0; kb < 128; kb += 32) {
            float4 u0 = *(const float4*)(p0 + half * 128 + kb);
            float4 u1 = *(const float4*)(p0 + half * 128 + kb + 4);
            float4 u2 = *(const float4*)(p1 + half * 128 + kb);
            float4 u3 = *(const float4*)(p1 + half * 128 + kb + 4);
            us8 a0u = { f2bf(u0.x), f2bf(u0.y), f2bf(u0.z), f2bf(u0.w),
                        f2bf(u1.x), f2bf(u1.y), f2bf(u1.z), f2bf(u1.w) };
            us8 a1u = { f2bf(u2.x), f2bf(u2.y), f2bf(u2.z), f2bf(u2.w),
                        f2bf(u3.x), f2bf(u3.y), f2bf(u3.z), f2bf(u3.w) };
            sh8 a0 = __builtin_bit_cast(sh8, a0u);
            sh8 a1 = __builtin_bit_cast(sh8, a1u);
            #pragma unroll
            for (int nt = 0; nt < 4; ++nt) {
                sh8 bb = *(const sh8*)(wt + (nt * 16 + m) * 136 + kb + g * 8);
                acc[0][nt] = __builtin_amdgcn_mfma_f32_16x16x32_bf16(a0, bb, acc[0][nt], 0, 0, 0);
                acc[1][nt] = __builtin_amdgcn_mfma_f32_16x16x32_bf16(a1, bb, acc[1][nt], 0, 0, 0);
            }
        }
    }

    #pragma unroll
    for (int mt = 0; mt < 2; ++mt) {
        #pragma unroll
        for (int r = 0; r < 4; ++r) {
            int gr = row0 + w * 32 + mt * 16 + (l >> 4) * 4 + r;
            if (gr < NN) {
                #pragma unroll
                for (int nt = 0; nt < 4; ++nt)
                    h1[(size_t)gr * HF + nt * 16 + (l & 15)] = f2bf(acc[mt][nt][r]);
            }
        }
    }
}

// ---- Gather layer 1: 8 nodes/wave, 8 lanes/node, lane owns 8 feats ---------
__global__ __launch_bounds__(256) void k_gather1(const int* __restrict__ rowptr,
                                                 const int* __restrict__ eidx,
                                                 const float* __restrict__ dinv,
                                                 const unsigned short* __restrict__ h1,
                                                 const float* __restrict__ b1,
                                                 const float* __restrict__ W2,
                                                 unsigned short* __restrict__ h2) {
    __shared__ float w2L[HF * OF];     // 4KB, [k][j]
    __shared__ float hrL[32][HF + 4];  // 8.5KB, stride 68 (bank-spread)
    int t = threadIdx.x;
    *(float4*)(w2L + t * 4) = *(const float4*)(W2 + t * 4);   // 256*4 = 1024 ✓

    int nodeL = t >> 3;           // 0..31: node within block
    int fg    = t & 7;            // feature octet: feats fg*8..fg*8+7
    int v     = blockIdx.x * 32 + nodeL;   // NN = 3125*32 exact
    int beg = rowptr[v], end = rowptr[v + 1];

    float acc[8] = {};
    int   s_n = 0;  float w_n = 0.f;  us8 h_n = {};
    if (beg < end) {
        s_n = eidx[beg];
        w_n = dinv[s_n];
        h_n = *(const us8*)(h1 + (size_t)s_n * HF + fg * 8);
    }
    for (int i = beg; i < end; ++i) {
        float w_c = w_n;  us8 h_c = h_n;
        if (i + 1 < end) {
            s_n = eidx[i + 1];
            w_n = dinv[s_n];
            h_n = *(const us8*)(h1 + (size_t)s_n * HF + fg * 8);
        }
        #pragma unroll
        for (int q = 0; q < 8; ++q) acc[q] += w_c * bf2f(h_c[q]);
    }

    {
        float dv = dinv[v], sl = dv * dv;
        us8 hv = *(const us8*)(h1 + (size_t)v * HF + fg * 8);
        #pragma unroll
        for (int q = 0; q < 8; ++q) {
            float val = dv * acc[q] + sl * bf2f(hv[q]) + b1[fg * 8 + q];
            hrL[nodeL][fg * 8 + q] = val > 0.f ? val : 0.f;
        }
    }
    __syncthreads();

    #pragma unroll
    for (int T = t; T < 512; T += 256) {
        int n = T >> 4, j = T & 15;
        const float* hr = hrL[n];
        float p = 0.f;
        #pragma unroll
        for (int k = 0; k < HF; ++k) p += hr[k] * w2L[k * OF + j];
        h2[(size_t)(blockIdx.x * 32 + n) * OF + j] = f2bf(p);
    }
}

// ---- Gather layer 2: 16 nodes/block, 16 lanes/node, lane owns 1 out-feat ---
__global__ __launch_bounds__(256) void k_gather2(const int* __restrict__ rowptr,
                                                 const int* __restrict__ eidx,
                                                 const float* __restrict__ dinv,
                                                 const unsigned short* __restrict__ h2,
                                                 const float* __restrict__ b2,
                                                 float* __restrict__ out) {
    int t     = threadIdx.x;
    int nodeL = t >> 4;           // 0..15
    int j     = t & 15;           // out-feature
    int v     = blockIdx.x * 16 + nodeL;   // NN = 6250*16 exact
    int beg = rowptr[v], end = rowptr[v + 1];

    float acc = 0.f;
    int   s_n = 0;  float w_n = 0.f;  unsigned short h_n = 0;
    if (beg < end) {
        s_n = eidx[beg];
        w_n = dinv[s_n];
        h_n = h2[(size_t)s_n * OF + j];
    }
    for (int i = beg; i < end; ++i) {
        float w_c = w_n;  unsigned short h_c = h_n;
        if (i + 1 < end) {
            s_n = eidx[i + 1];
            w_n = dinv[s_n];
            h_n = h2[(size_t)s_n * OF + j];
        }
        acc += w_c * bf2f(h_c);
    }
    float dv = dinv[v];
    out[(size_t)v * OF + j] = dv * acc + dv * dv * bf2f(h2[(size_t)v * OF + j]) + b2[j];
}

extern "C" void kernel_launch(void* const* d_in, const int* in_sizes, int n_in,
                              void* d_out, int out_size, void* d_ws, size_t ws_size,
                              hipStream_t stream) {
    const float* x   = (const float*)d_in[0];
    const int*   ei  = (const int*)d_in[1];
    const int*   src = ei;            // edge_index[0]
    const int*   dst = ei + NE;       // edge_index[1]
    const float* W1  = (const float*)d_in[2];
    const float* b1  = (const float*)d_in[3];
    const float* W2  = (const float*)d_in[4];
    const float* b2  = (const float*)d_in[5];
    float* out = (float*)d_out;

    // workspace layout (4B units unless noted)
    float* dinv  = (float*)d_ws;                           // [CNTW]
    unsigned short* h1b = (unsigned short*)(dinv + CNTW);  // [NN*64] bf16 (3.2M ints)
    unsigned short* h2b = (unsigned short*)(h1b + (size_t)NN * HF);  // [NN*16] bf16
    int*   cnt   = (int*)(h2b + (size_t)NN * OF + (size_t)NN * OF);  // [CNTW]
    int*   rowptr = cnt + CNTW;                            // [100352]
    int*   cursor = rowptr + 100352;                       // [CNTW]
    int*   eidx  = cursor + CNTW;                          // [NE]
    int*   bsum  = eidx + NE;                              // [128]
    unsigned short* wt_g = (unsigned short*)(bsum + 128);  // [64*256] bf16

    // CSR build + norms + W pre-transpose
    k_pre<<<ZBLK + 64, 256, 0, stream>>>(cnt, W1, wt_g);
    k_hist<<<SB, 256, 0, stream>>>(dst, cnt);
    k_reduce<<<NBLK, 256, 0, stream>>>(cnt, bsum, dinv);
    k_scan<<<NBLK, 256, 0, stream>>>(cnt, bsum, rowptr, cursor);

    // gemm1 || scatter in one launch (independent work, overlap on one stream)
    k_gs<<<GB + SB, 256, 0, stream>>>(x, wt_g, h1b, src, dst, cursor, eidx);

    // layer 1 aggregation (+ fused layer-2 GEMM)
    k_gather1<<<NN / 32, 256, 0, stream>>>(rowptr, eidx, dinv, h1b, b1, W2, h2b);

    // layer 2 aggregation
    k_gather2<<<NN / 16, 256, 0, stream>>>(rowptr, eidx, dinv, h2b, b2, out);
}